// Round 12
// baseline (669.005 us; speedup 1.0000x reference)
//
#include <hip/hip_runtime.h>

#define LF 8192
#define NB 8
#define NC 512
#define NA 7
#define NANCH 57344        // LF*NA
#define PRE_K 600
#define POST_K 100

// output layout (floats), concatenated in reference return order
#define OBJ_OFF   0
#define REG_OFF   458752
#define ANCH_OFF  1376256
#define PROPS_OFF 1490944
#define PSC_OFF   1492544
#define PM_OFF    1493344

// workspace layout (bytes)
#define WF_BYTES   3145728          // prefragmented split-bf16 weights
#define GHIST_OFF  WF_BYTES         // 8 batches x 65536 bins x 4B = 2 MB
#define GHIST_BYTES (8 * 65536 * 4)

typedef __attribute__((ext_vector_type(8))) short bf16x8;
typedef __attribute__((ext_vector_type(4))) float f32x4;

__device__ __forceinline__ unsigned short f2bf(float f) {   // RNE float->bf16
  unsigned u = __float_as_uint(f);
  u += 0x7fff + ((u >> 16) & 1);
  return (unsigned short)(u >> 16);
}
__device__ __forceinline__ float bf2f(unsigned short h) {
  return __uint_as_float(((unsigned)h) << 16);
}

// packed split-bf16 convert: hw = bf16(v0)|bf16(v1)<<16, lw = residual pair.
__device__ __forceinline__ void cvt_split(float v0, float v1,
                                          unsigned& hw, unsigned& lw) {
  asm("v_cvt_pk_bf16_f32 %0, %1, %2" : "=v"(hw) : "v"(v0), "v"(v1));
  float h0f = __uint_as_float(hw << 16);
  float h1f = __uint_as_float(hw & 0xffff0000u);
  asm("v_cvt_pk_bf16_f32 %0, %1, %2" : "=v"(lw) : "v"(v0 - h0f), "v"(v1 - h1f));
}

// ---- weight prep: conv_w[co][ci][tap] -> split-bf16, MFMA-A-fragment order ----
// layout: [cc=cob*16+chunk (64)][tap 3][cotl 8][split 2][lane 64][j 8]
// frag semantics: co = cob*128 + cotl*16 + (lane&15); ci = chunk*32 + (lane>>4)*8 + j
// anchors + output-zeroing + ghist-zeroing fused in (saves 1 launch + 2 memsets).
__global__ void prep_w_k(const float* __restrict__ cw, unsigned short* __restrict__ wf,
                         float* __restrict__ out, unsigned* __restrict__ ghist) {
  int o = blockIdx.x * 256 + threadIdx.x;      // 786432 items (both splits per item)
  {
    size_t z = 2 * (size_t)o;
    if (z < ANCH_OFF) {
      out[z] = 0.f;
      if (z + 1 < ANCH_OFF) out[z + 1] = 0.f;
    }
  }
  if (o < 8 * 65536) ghist[o] = 0u;            // fused ghist zero
  if (o < NANCH) {                             // fused anchors
    int l = o / 7, a = o - l * 7;
    float len = (float)(a + 1 + (a > 4 ? a - 4 : 0));   // {1,2,3,4,5,7,9}
    float c = (float)l + 0.5f;
    out[ANCH_OFF + 2 * (size_t)o]     = c - 0.5f * len;
    out[ANCH_OFF + 2 * (size_t)o + 1] = c + 0.5f * len;
  }
  if (o >= 786432) return;
  int j    = o & 7;
  int lane = (o >> 3) & 63;
  int cotl = (o >> 9) & 7;
  int rem  = o >> 12;                          // cc*3 + tap, 0..191
  int tap  = rem % 3;
  int cc   = rem / 3;                          // cob*16 + chunk
  int co = (cc >> 4) * 128 + cotl * 16 + (lane & 15);
  int ci = (cc & 15) * 32 + (lane >> 4) * 8 + j;
  float w = cw[((size_t)co * 512 + ci) * 3 + tap];
  unsigned short hi = f2bf(w);
  unsigned short lo = f2bf(w - bf2f(hi));
  size_t base = ((((size_t)rem * 8 + cotl) * 2) * 64 + lane) * 8 + j;
  wf[base] = hi;
  wf[base + 512] = lo;                         // split stride = 64*8
}

// ---- split-bf16 MFMA conv + ReLU + projection ---------------------------------
// R12: M128xN32 PER-WAVE TILE (was M64xN64). R11's counters proved conv is
// LDS-READ-BOUND: B-frag reads ~288KB/chunk/CU (~3400cyc@85B/cyc) vs MFMA
// 2094cyc/SIMD. Reshaping the wave tile keeps outputs (4096 -> acc 64 VGPR)
// and MFMA count constant but HALVES B reads (12 b128/wave/chunk, N=32) and
// removes cross-wave B duplication (waves own disjoint col ranges). A-reads
// double (48 b128/wave, x4 dup) but come from L2 (~6.5 TB/s << 34.5 cap).
// A ping-pongs per (tap, m-half): 2x32 VGPR as before; B shrinks 32->8 VGPR.
// grid (64 l-tiles, 4 cob, 4 b) x 2 dispatches, 256 threads (4 waves = 4 col
// groups of 32). Staging/LDS layout/projection unchanged from R10.
// HARD LAW: VGPR <=128. CAP LAW: no 2nd __launch_bounds__ arg. R11 lesson:
// keep independent 4-wave blocks (cross-block overlap), don't merge waves.
#define BUFSH 10400   // shorts per buffer (fhi 5200 + flo 5200)
__global__ __launch_bounds__(256) void conv_proj_k(
    const float* __restrict__ feat, const unsigned short* __restrict__ wfrag,
    const float* __restrict__ cbias, const float* __restrict__ obj_w,
    const float* __restrict__ obj_b, const float* __restrict__ reg_w,
    const float* __restrict__ reg_b, float* __restrict__ out, int bbase)
{
  __shared__ __align__(16) char smem[41600];   // 2 feat buffers; epilogue bufp aliases
  unsigned short* sb = (unsigned short*)smem;
  float* bufp = (float*)smem;                  // [64][130] (33280 B, aliases bufs)

  const int tid  = threadIdx.x;
  const int l0   = blockIdx.x * 128;
  const int cob  = blockIdx.y;
  const int b    = bbase + blockIdx.z;
  const int lane = tid & 63, wave = tid >> 6;  // wave = col group (32 cols each)
  const int quad = lane >> 4, l15 = lane & 15;

  const float* fb = feat + (size_t)b * 512 * LF;
  const bf16x8* wf8 = (const bf16x8*)wfrag;

  f32x4 acc[8][2];                             // [mt 0..7 = 128 rows][nt 0..1 = 32 cols]
  #pragma unroll
  for (int mt = 0; mt < 8; ++mt)
    #pragma unroll
    for (int nt = 0; nt < 2; ++nt) acc[mt][nt] = (f32x4){0.f, 0.f, 0.f, 0.f};

  const int r8 = tid & 7, cp2 = (tid >> 3) & 15, set = tid >> 7;

  // boundary-thread geometry (tid < 32 handles rows 0 and 129)
  const int brr = tid >> 4, bc2 = tid & 15;
  const int bl = (brr == 0) ? (l0 - 1) : (l0 + 128);
  const bool bok = (bl >= 0) && (bl < LF);

  float pv0[8], pv1[8], bv0 = 0.f, bv1 = 0.f;

  auto prefetch = [&](int ch) {
    const int cb = ch * 32;
    #pragma unroll
    for (int p = 0; p < 8; ++p) {
      int l = l0 + p * 16 + set * 8 + r8;
      pv0[p] = fb[(size_t)(cb + 2 * cp2) * LF + l];
      pv1[p] = fb[(size_t)(cb + 2 * cp2 + 1) * LF + l];
    }
    if (tid < 32 && bok) {
      bv0 = fb[(size_t)(cb + 2 * bc2) * LF + bl];
      bv1 = fb[(size_t)(cb + 2 * bc2 + 1) * LF + bl];
    }
  };
  auto stage = [&](int bi) {       // convert pv/bv -> LDS buffer bi (packed cvt)
    unsigned short* fh = sb + bi * BUFSH;
    unsigned short* fl = fh + 5200;
    #pragma unroll
    for (int p = 0; p < 8; ++p) {
      int row = p * 16 + set * 8 + r8;
      unsigned hw, lw;
      cvt_split(pv0[p], pv1[p], hw, lw);
      int e = (row + 1) * 40 + 2 * cp2;
      *(unsigned*)(fh + e) = hw;
      *(unsigned*)(fl + e) = lw;
    }
    if (tid < 32) {
      unsigned hw, lw;
      cvt_split(bv0, bv1, hw, lw);
      int e = (brr * 129) * 40 + 2 * bc2;
      *(unsigned*)(fh + e) = hw;
      *(unsigned*)(fl + e) = lw;
    }
  };

  // prologue: buf0 <- chunk0; regs <- chunk1
  prefetch(0);
  stage(0);
  prefetch(1);
  __syncthreads();

  for (int chunk = 0; chunk < 16; ++chunk) {
    const unsigned short* fh = sb + (chunk & 1) * BUFSH;
    const unsigned short* fl = fh + 5200;
    const int rem3 = (cob * 16 + chunk) * 3;

    bf16x8 AhA[4], AlA[4], AhB[4], AlB[4];   // 2-set ping-pong (static names, rule #20)
    bf16x8 Bh[2], Bl[2];                     // per-tap B, reused across both m-halves

    auto loadA = [&](int tap, int mh, bf16x8* AH, bf16x8* AL) {
      #pragma unroll
      for (int mt2 = 0; mt2 < 4; ++mt2) {
        int fi = (((rem3 + tap) * 8 + mh * 4 + mt2) * 2) * 64 + lane;
        AH[mt2] = wf8[fi];
        AL[mt2] = wf8[fi + 64];
      }
    };
    auto loadB = [&](int tap) {
      #pragma unroll
      for (int nt = 0; nt < 2; ++nt) {
        int row = wave * 32 + nt * 16 + l15 + tap;
        int e = row * 40 + quad * 8;
        Bh[nt] = *(const bf16x8*)(fh + e);
        Bl[nt] = *(const bf16x8*)(fl + e);
      }
    };
    auto mfma_blk = [&](int mh, const bf16x8* AH, const bf16x8* AL) {
      __builtin_amdgcn_s_setprio(1);
      #pragma unroll
      for (int mt2 = 0; mt2 < 4; ++mt2)
        #pragma unroll
        for (int nt = 0; nt < 2; ++nt) {
          acc[mh * 4 + mt2][nt] = __builtin_amdgcn_mfma_f32_16x16x32_bf16(AH[mt2], Bh[nt], acc[mh * 4 + mt2][nt], 0, 0, 0);
          acc[mh * 4 + mt2][nt] = __builtin_amdgcn_mfma_f32_16x16x32_bf16(AH[mt2], Bl[nt], acc[mh * 4 + mt2][nt], 0, 0, 0);
          acc[mh * 4 + mt2][nt] = __builtin_amdgcn_mfma_f32_16x16x32_bf16(AL[mt2], Bh[nt], acc[mh * 4 + mt2][nt], 0, 0, 0);
        }
      __builtin_amdgcn_s_setprio(0);
    };

    loadA(0, 0, AhA, AlA);              // tap0 mh0: latency hides under stage()
    if (chunk < 15) stage((chunk + 1) & 1);
    loadB(0);
    loadA(0, 1, AhB, AlB);              // tap0 mh1 in flight during mh0 MFMAs
    __builtin_amdgcn_sched_barrier(0);
    mfma_blk(0, AhA, AlA);              // tap0 mh0
    loadA(1, 0, AhA, AlA);
    __builtin_amdgcn_sched_barrier(0);
    mfma_blk(1, AhB, AlB);              // tap0 mh1 (B tap0 last use)
    loadB(1);
    loadA(1, 1, AhB, AlB);
    __builtin_amdgcn_sched_barrier(0);
    mfma_blk(0, AhA, AlA);              // tap1 mh0
    loadA(2, 0, AhA, AlA);
    __builtin_amdgcn_sched_barrier(0);
    mfma_blk(1, AhB, AlB);              // tap1 mh1 (B tap1 last use)
    loadB(2);
    loadA(2, 1, AhB, AlB);
    if (chunk < 14) prefetch(chunk + 2);  // youngest: stays in flight across waits
    __builtin_amdgcn_sched_barrier(0);
    mfma_blk(0, AhA, AlA);              // tap2 mh0
    mfma_blk(1, AhB, AlB);              // tap2 mh1
    __syncthreads();
  }

  // ---- epilogue: bias + relu -> LDS half-tiles -> 21-row projection -----------
  // All waves write each h-half (rows h*64..+63 of their 32 cols) -- uniform
  // barrier structure, no wm gating.
  const int sg = tid >> 5;           // 0..7 -> rows 3sg..3sg+2
  const int ll = tid & 31;
  int rc0 = 3 * sg     < 21 ? 3 * sg     : 20;
  int rc1 = 3 * sg + 1 < 21 ? 3 * sg + 1 : 20;
  int rc2 = 3 * sg + 2 < 21 ? 3 * sg + 2 : 20;
  const float* wr0 = (rc0 < 7) ? (obj_w + (size_t)rc0 * 512) : (reg_w + (size_t)(rc0 - 7) * 512);
  const float* wr1 = (rc1 < 7) ? (obj_w + (size_t)rc1 * 512) : (reg_w + (size_t)(rc1 - 7) * 512);
  const float* wr2 = (rc2 < 7) ? (obj_w + (size_t)rc2 * 512) : (reg_w + (size_t)(rc2 - 7) * 512);
  float pacc[3][4];
  #pragma unroll
  for (int q = 0; q < 3; ++q)
    #pragma unroll
    for (int m = 0; m < 4; ++m) pacc[q][m] = 0.f;

  #pragma unroll
  for (int h = 0; h < 2; ++h) {
    __syncthreads();
    #pragma unroll
    for (int mt2 = 0; mt2 < 4; ++mt2) {
      f32x4 bv = *(const f32x4*)(cbias + cob * 128 + h * 64 + mt2 * 16 + quad * 4);
      #pragma unroll
      for (int nt = 0; nt < 2; ++nt) {
        int col = wave * 32 + nt * 16 + l15;
        #pragma unroll
        for (int r = 0; r < 4; ++r)
          bufp[(mt2 * 16 + quad * 4 + r) * 130 + col] = fmaxf(acc[h * 4 + mt2][nt][r] + bv[r], 0.f);
      }
    }
    __syncthreads();
    for (int c = 0; c < 64; ++c) {
      int cg = cob * 128 + h * 64 + c;
      float w0 = wr0[cg], w1 = wr1[cg], w2 = wr2[cg];
      #pragma unroll
      for (int m = 0; m < 4; ++m) {
        float hv = bufp[c * 130 + ll + 32 * m];
        pacc[0][m] = fmaf(w0, hv, pacc[0][m]);
        pacc[1][m] = fmaf(w1, hv, pacc[1][m]);
        pacc[2][m] = fmaf(w2, hv, pacc[2][m]);
      }
    }
  }

  const size_t ob = (size_t)b * NANCH;
  #pragma unroll
  for (int q = 0; q < 3; ++q) {
    int r = 3 * sg + q;
    if (r < 21) {
      #pragma unroll
      for (int m = 0; m < 4; ++m) {
        int l = l0 + ll + 32 * m;
        float v = pacc[q][m] + ((cob == 0) ? ((r < 7) ? obj_b[r] : reg_b[r - 7]) : 0.f);
        if (r < 7) atomicAdd(&out[OBJ_OFF + ob + (size_t)l * 7 + r], v);
        else { int rr = r - 7; atomicAdd(&out[REG_OFF + (ob + (size_t)l * 7 + (rr >> 1)) * 2 + (rr & 1)], v); }
      }
    }
  }
}

// monotone sortable bits of a float logit (total order == value order)
__device__ __forceinline__ unsigned keybits(float x) {
  unsigned u = __float_as_uint(x);
  return (u & 0x80000000u) ? ~u : (u | 0x80000000u);
}

// ---- full-chip 16-bit-key histogram (per batch), byte-swapped bin storage -----
__global__ __launch_bounds__(256) void hist_k(const float* __restrict__ out,
                                              unsigned* __restrict__ ghist) {
  const int b = blockIdx.y;
  const float* obj = out + OBJ_OFF + (size_t)b * NANCH;
  unsigned* h = ghist + (size_t)b * 65536;
  const int base = blockIdx.x * 256 + threadIdx.x;   // grid.x = 28; 28*256*8 = NANCH
  float v[8];
  #pragma unroll
  for (int k = 0; k < 8; ++k) v[k] = obj[base + k * 7168];
  #pragma unroll
  for (int k = 0; k < 8; ++k) {
    unsigned bin = keybits(v[k]) >> 16;
    unsigned phys = ((bin & 255u) << 8) | (bin >> 8);
    atomicAdd(&h[phys], 1u);
  }
}

// ---------------- per-batch top-600 -> NMS -> top-100, 1024 threads ------------
// (R10-verified; LDS 60.4 KB, all barriers full-block.)
__global__ __launch_bounds__(1024) void propose_k(float* __restrict__ out,
                                                  const unsigned* __restrict__ ghist) {
  const int b = blockIdx.x;
  const int tid = threadIdx.x;
  const int lane = tid & 63;
  const int wave = tid >> 6;

  __shared__ unsigned long long pool[PRE_K * 10];  // 48 KB; first 1024 = sort keys
  __shared__ unsigned part[1024];
  __shared__ unsigned coarse[256];
  __shared__ float bs[PRE_K], be[PRE_K], bsc[PRE_K];
  __shared__ unsigned long long vwords[10];
  __shared__ int scal[6];

  unsigned long long* keys = pool;
  const float* obj = out + OBJ_OFF + (size_t)b * NANCH;
  const unsigned* gh = ghist + (size_t)b * 65536;

  if (tid < 10) vwords[tid] = 0ull;
  if (tid == 0) scal[2] = 0;

  // ---- stage 1: per-high8 sums, 4 partials per hi8 (coalesced via byteswap) ----
  {
    const int q = tid >> 8, h8 = tid & 255;
    unsigned s = 0;
    #pragma unroll 8
    for (int lo = 0; lo < 64; ++lo) s += gh[((unsigned)(q * 64 + lo) << 8) | (unsigned)h8];
    part[tid] = s;
  }
  __syncthreads();
  if (tid < 256) coarse[tid] = part[tid] + part[tid + 256] + part[tid + 512] + part[tid + 768];
  __syncthreads();
  for (int off = 1; off < 256; off <<= 1) {       // inclusive suffix scan
    unsigned v = 0, add = 0;
    if (tid < 256) { v = coarse[tid]; add = (tid + off < 256) ? coarse[tid + off] : 0u; }
    __syncthreads();
    if (tid < 256) coarse[tid] = v + add;
    __syncthreads();
  }
  if (tid < 256) {
    unsigned sfx  = coarse[tid];
    unsigned sfx1 = (tid < 255) ? coarse[tid + 1] : 0u;
    if (sfx >= (unsigned)PRE_K && sfx1 < (unsigned)PRE_K) { scal[0] = tid; scal[1] = (int)sfx1; }
  }
  __syncthreads();
  const int hi8 = scal[0];
  const int before1 = scal[1];
  __syncthreads();
  // ---- stage 2: refine within the winning 256-bin range ----
  if (tid < 256) coarse[tid] = gh[((unsigned)tid << 8) | (unsigned)hi8];
  __syncthreads();
  for (int off = 1; off < 256; off <<= 1) {
    unsigned v = 0, add = 0;
    if (tid < 256) { v = coarse[tid]; add = (tid + off < 256) ? coarse[tid + off] : 0u; }
    __syncthreads();
    if (tid < 256) coarse[tid] = v + add;
    __syncthreads();
  }
  if (tid < 256) {
    unsigned sfx  = coarse[tid];
    unsigned sfx1 = (tid < 255) ? coarse[tid + 1] : 0u;
    if (before1 + (int)sfx >= PRE_K && before1 + (int)sfx1 < PRE_K) scal[4] = tid;
  }
  __syncthreads();
  const unsigned Tbits = ((((unsigned)hi8 << 8) | (unsigned)scal[4]) << 16);

  // ---- compaction: single pass, 7 x 8 coalesced loads in flight ----
  for (int it = 0; it < 7; ++it) {               // 7 * 8192 = NANCH
    float v[8];
    #pragma unroll
    for (int k = 0; k < 8; ++k) v[k] = obj[it * 8192 + k * 1024 + tid];
    #pragma unroll
    for (int k = 0; k < 8; ++k) {
      unsigned u = keybits(v[k]);
      if (u >= Tbits) {
        int p = atomicAdd(&scal[2], 1);
        if (p < 1024)
          keys[p] = ((unsigned long long)u << 32) |
                    (unsigned long long)(~(unsigned)(it * 8192 + k * 1024 + tid));
      }
    }
  }
  __syncthreads();
  const int cnt = scal[2];
  if (tid >= cnt) keys[tid] = 0ull;
  // ---- bitonic sort, 1 element per thread ----
  for (unsigned k = 2; k <= 1024; k <<= 1) {
    for (unsigned j = k >> 1; j > 0; j >>= 1) {
      __syncthreads();
      unsigned idx = tid, partner = idx ^ j;
      if (partner > idx) {
        unsigned long long a = keys[idx], c = keys[partner];
        bool up = ((idx & k) == 0);
        if (up ? (a < c) : (a > c)) { keys[idx] = c; keys[partner] = a; }
      }
    }
  }
  __syncthreads();
  // ---- decode top-600 ----
  if (tid < PRE_K) {
    const int t = tid;
    unsigned long long kv = keys[t];
    unsigned u  = (unsigned)(kv >> 32);
    unsigned i2 = ~((unsigned)kv);
    unsigned ub = (u & 0x80000000u) ? (u & 0x7fffffffu) : ~u;
    float logit = __uint_as_float(ub);
    float score = 1.f / (1.f + expf(-logit));
    int li = (int)(i2 / 7u);
    int a  = (int)(i2 - (unsigned)li * 7u);
    float alen = (float)(a + 1 + (a > 4 ? a - 4 : 0));
    const float* rp = out + REG_OFF + ((size_t)b * NANCH + i2) * 2;
    float tc = rp[0];
    float tw = fminf(fmaxf(rp[1], -10.f), 10.f);
    float cc = (float)li + 0.5f + tc * alen;
    float ww = alen * expf(tw);
    float s0 = cc - 0.5f * ww;
    float e0 = cc + 0.5f * ww;
    s0 = fminf(fmaxf(s0, 0.f), (float)LF);
    e0 = fminf(fmaxf(e0, 0.f), (float)LF);
    e0 = fminf(fmaxf(e0, s0 + 1e-3f), (float)LF);
    s0 = fmaxf(fminf(s0, e0 - 1e-3f), 0.f);
    bs[t] = s0; be[t] = e0; bsc[t] = score;
    if (score >= 0.1f) atomicOr(&vwords[t >> 6], 1ull << (t & 63));
  }
  __syncthreads();
  // ---- IoU suppression mask (row-major 64-bit words) ----
  for (int widx = tid; widx < PRE_K * 10; widx += 1024) {
    int j = widx / 10;
    int w = widx - j * 10;
    int base = w * 64;
    unsigned long long m = 0ull;
    if (base + 63 > j) {
      float sj = bs[j], ej = be[j];
      float wj = ej - sj;
      for (int bit = 0; bit < 64; ++bit) {
        int i3 = base + bit;
        if (i3 > j && i3 < PRE_K) {
          float inter = fmaxf(fminf(ej, be[i3]) - fmaxf(sj, bs[i3]), 0.f);
          float uni = wj + (be[i3] - bs[i3]) - inter;
          float iou = inter / fmaxf(uni, 1e-6f);
          if (iou > 0.5f) m |= (1ull << bit);
        }
      }
    }
    pool[widx] = m;
  }
  __syncthreads();
  // ---- serial NMS sweep (wave 0; early-exit at kept=100) ----
  if (wave == 0) {
    unsigned long long rem = 0ull;
    unsigned long long vw = (lane < 10) ? vwords[lane] : 0ull;
    unsigned long long mrow = (lane < 10) ? pool[lane] : 0ull;
    int kept = 0;
    for (int i3 = 0; i3 < PRE_K; ++i3) {
      unsigned long long mnext =
          (lane < 10 && (i3 + 1) < PRE_K) ? pool[(i3 + 1) * 10 + lane] : 0ull;
      unsigned long long avail = vw & ~rem;
      unsigned long long ow = __shfl(avail, i3 >> 6);
      if ((ow >> (i3 & 63)) & 1ull) {
        rem |= mrow;
        if (lane == 0) {
          out[PROPS_OFF + (size_t)b * 200 + 2 * kept]     = bs[i3];
          out[PROPS_OFF + (size_t)b * 200 + 2 * kept + 1] = be[i3];
          out[PSC_OFF + (size_t)b * 100 + kept] = bsc[i3];
          out[PM_OFF  + (size_t)b * 100 + kept] = 1.0f;
        }
        ++kept;
        if (kept >= POST_K) break;
      }
      mrow = mnext;
    }
    if (lane == 0) scal[3] = kept;
  }
  __syncthreads();
  const int kf = scal[3];
  if (tid < POST_K && tid >= kf) {
    out[PROPS_OFF + (size_t)b * 200 + 2 * tid]     = 0.f;
    out[PROPS_OFF + (size_t)b * 200 + 2 * tid + 1] = 0.f;
    out[PSC_OFF + (size_t)b * 100 + tid] = 0.f;
    out[PM_OFF  + (size_t)b * 100 + tid] = 0.f;
  }
}

extern "C" void kernel_launch(void* const* d_in, const int* in_sizes, int n_in,
                              void* d_out, int out_size, void* d_ws, size_t ws_size,
                              hipStream_t stream) {
  const float* feat = (const float*)d_in[0];
  const float* cw   = (const float*)d_in[1];
  const float* cb   = (const float*)d_in[2];
  const float* ow   = (const float*)d_in[3];
  const float* obb  = (const float*)d_in[4];
  const float* rw   = (const float*)d_in[5];
  const float* rb   = (const float*)d_in[6];
  float* out = (float*)d_out;
  unsigned short* wf = (unsigned short*)d_ws;   // 3.14 MB prefragmented split-bf16 weights
  unsigned* ghist = (unsigned*)((char*)d_ws + GHIST_OFF);

  hipLaunchKernelGGL(prep_w_k, dim3(3072), dim3(256), 0, stream, cw, wf, out, ghist);
  hipLaunchKernelGGL(conv_proj_k, dim3(64, 4, 4), dim3(256), 0, stream,
                     feat, wf, cb, ow, obb, rw, rb, out, 0);
  hipLaunchKernelGGL(conv_proj_k, dim3(64, 4, 4), dim3(256), 0, stream,
                     feat, wf, cb, ow, obb, rw, rb, out, 4);
  hipLaunchKernelGGL(hist_k, dim3(28, 8), dim3(256), 0, stream, out, ghist);
  hipLaunchKernelGGL(propose_k, dim3(8), dim3(1024), 0, stream, out, ghist);
}

// Round 13
// 610.987 us; speedup vs baseline: 1.0950x; 1.0950x over previous
//
#include <hip/hip_runtime.h>

#define LF 8192
#define NB 8
#define NC 512
#define NA 7
#define NANCH 57344        // LF*NA
#define PRE_K 600
#define POST_K 100

// output layout (floats), concatenated in reference return order
#define OBJ_OFF   0
#define REG_OFF   458752
#define ANCH_OFF  1376256
#define PROPS_OFF 1490944
#define PSC_OFF   1492544
#define PM_OFF    1493344

// workspace layout (bytes)
#define WF_BYTES   3145728          // prefragmented split-bf16 weights
#define GHIST_OFF  WF_BYTES         // 8 batches x 65536 bins x 4B = 2 MB
#define GHIST_BYTES (8 * 65536 * 4)

typedef __attribute__((ext_vector_type(8))) short bf16x8;
typedef __attribute__((ext_vector_type(4))) float f32x4;

__device__ __forceinline__ unsigned short f2bf(float f) {   // RNE float->bf16
  unsigned u = __float_as_uint(f);
  u += 0x7fff + ((u >> 16) & 1);
  return (unsigned short)(u >> 16);
}
__device__ __forceinline__ float bf2f(unsigned short h) {
  return __uint_as_float(((unsigned)h) << 16);
}

// packed split-bf16 convert: hw = bf16(v0)|bf16(v1)<<16, lw = residual pair.
__device__ __forceinline__ void cvt_split(float v0, float v1,
                                          unsigned& hw, unsigned& lw) {
  asm("v_cvt_pk_bf16_f32 %0, %1, %2" : "=v"(hw) : "v"(v0), "v"(v1));
  float h0f = __uint_as_float(hw << 16);
  float h1f = __uint_as_float(hw & 0xffff0000u);
  asm("v_cvt_pk_bf16_f32 %0, %1, %2" : "=v"(lw) : "v"(v0 - h0f), "v"(v1 - h1f));
}

// ---- weight prep: conv_w[co][ci][tap] -> split-bf16, MFMA-A-fragment order ----
// layout: [cc=cob*16+chunk (64)][tap 3][cotl 8][split 2][lane 64][j 8]
// frag semantics: co = cob*128 + cotl*16 + (lane&15); ci = chunk*32 + (lane>>4)*8 + j
// anchors + output-zeroing + ghist-zeroing fused in (saves 1 launch + 2 memsets).
__global__ void prep_w_k(const float* __restrict__ cw, unsigned short* __restrict__ wf,
                         float* __restrict__ out, unsigned* __restrict__ ghist) {
  int o = blockIdx.x * 256 + threadIdx.x;      // 786432 items (both splits per item)
  {
    size_t z = 2 * (size_t)o;
    if (z < ANCH_OFF) {
      out[z] = 0.f;
      if (z + 1 < ANCH_OFF) out[z + 1] = 0.f;
    }
  }
  if (o < 8 * 65536) ghist[o] = 0u;            // fused ghist zero
  if (o < NANCH) {                             // fused anchors
    int l = o / 7, a = o - l * 7;
    float len = (float)(a + 1 + (a > 4 ? a - 4 : 0));   // {1,2,3,4,5,7,9}
    float c = (float)l + 0.5f;
    out[ANCH_OFF + 2 * (size_t)o]     = c - 0.5f * len;
    out[ANCH_OFF + 2 * (size_t)o + 1] = c + 0.5f * len;
  }
  if (o >= 786432) return;
  int j    = o & 7;
  int lane = (o >> 3) & 63;
  int cotl = (o >> 9) & 7;
  int rem  = o >> 12;                          // cc*3 + tap, 0..191
  int tap  = rem % 3;
  int cc   = rem / 3;                          // cob*16 + chunk
  int co = (cc >> 4) * 128 + cotl * 16 + (lane & 15);
  int ci = (cc & 15) * 32 + (lane >> 4) * 8 + j;
  float w = cw[((size_t)co * 512 + ci) * 3 + tap];
  unsigned short hi = f2bf(w);
  unsigned short lo = f2bf(w - bf2f(hi));
  size_t base = ((((size_t)rem * 8 + cotl) * 2) * 64 + lane) * 8 + j;
  wf[base] = hi;
  wf[base + 512] = lo;                         // split stride = 64*8
}

// ---- split-bf16 MFMA conv + ReLU + projection ---------------------------------
// R13: REVERT to the R10-proven structure (best measured: 185us/half, 634 total)
// as a single (64,4,8) dispatch (R7 evidence: single dispatch 362 < 370 split,
// and propose_k visibility is no longer needed -- it measured <184us).
// M64xN64 per-wave tile, 2-set A ping-pong, 112 VGPR, occ ~22%, MfmaUtil ~38%.
// Experiment ledger (all falsified, do NOT retry): R3 dbuf+setprio +2%;
// R5 cvt_pk staging VALU 0%; R7 A-ping-pong +4%; R4/R6 wider reg tiles
// (160/140 VGPR -> occupancy halved, -30%); R11 8-wave merge -16%;
// R12 M128xN32 reshape -12% (LDS-B-read theory falsified by counters).
// The ~37-38% MfmaUtil wall is this 2-barrier structure's ceiling (m97-type);
// past it requires the full 8-phase co-designed schedule.
// HARD LAW: VGPR <=128. CAP LAW: no 2nd __launch_bounds__ arg.
#define BUFSH 10400   // shorts per buffer (fhi 5200 + flo 5200)
__global__ __launch_bounds__(256) void conv_proj_k(
    const float* __restrict__ feat, const unsigned short* __restrict__ wfrag,
    const float* __restrict__ cbias, const float* __restrict__ obj_w,
    const float* __restrict__ obj_b, const float* __restrict__ reg_w,
    const float* __restrict__ reg_b, float* __restrict__ out)
{
  __shared__ __align__(16) char smem[41600];   // 2 feat buffers; epilogue bufp aliases
  unsigned short* sb = (unsigned short*)smem;
  float* bufp = (float*)smem;                  // [64][130] (33280 B, aliases bufs)

  const int tid  = threadIdx.x;
  const int l0   = blockIdx.x * 128;
  const int cob  = blockIdx.y;
  const int b    = blockIdx.z;
  const int lane = tid & 63, wave = tid >> 6;
  const int wm = wave >> 1, wn = wave & 1;
  const int quad = lane >> 4, l15 = lane & 15;

  const float* fb = feat + (size_t)b * 512 * LF;
  const bf16x8* wf8 = (const bf16x8*)wfrag;

  f32x4 acc[4][4];
  #pragma unroll
  for (int mt = 0; mt < 4; ++mt)
    #pragma unroll
    for (int nt = 0; nt < 4; ++nt) acc[mt][nt] = (f32x4){0.f, 0.f, 0.f, 0.f};

  const int r8 = tid & 7, cp2 = (tid >> 3) & 15, set = tid >> 7;

  // boundary-thread geometry (tid < 32 handles rows 0 and 129)
  const int brr = tid >> 4, bc2 = tid & 15;
  const int bl = (brr == 0) ? (l0 - 1) : (l0 + 128);
  const bool bok = (bl >= 0) && (bl < LF);

  float pv0[8], pv1[8], bv0 = 0.f, bv1 = 0.f;

  auto prefetch = [&](int ch) {
    const int cb = ch * 32;
    #pragma unroll
    for (int p = 0; p < 8; ++p) {
      int l = l0 + p * 16 + set * 8 + r8;
      pv0[p] = fb[(size_t)(cb + 2 * cp2) * LF + l];
      pv1[p] = fb[(size_t)(cb + 2 * cp2 + 1) * LF + l];
    }
    if (tid < 32 && bok) {
      bv0 = fb[(size_t)(cb + 2 * bc2) * LF + bl];
      bv1 = fb[(size_t)(cb + 2 * bc2 + 1) * LF + bl];
    }
  };
  auto stage = [&](int bi) {       // convert pv/bv -> LDS buffer bi (packed cvt)
    unsigned short* fh = sb + bi * BUFSH;
    unsigned short* fl = fh + 5200;
    #pragma unroll
    for (int p = 0; p < 8; ++p) {
      int row = p * 16 + set * 8 + r8;
      unsigned hw, lw;
      cvt_split(pv0[p], pv1[p], hw, lw);
      int e = (row + 1) * 40 + 2 * cp2;
      *(unsigned*)(fh + e) = hw;
      *(unsigned*)(fl + e) = lw;
    }
    if (tid < 32) {
      unsigned hw, lw;
      cvt_split(bv0, bv1, hw, lw);
      int e = (brr * 129) * 40 + 2 * bc2;
      *(unsigned*)(fh + e) = hw;
      *(unsigned*)(fl + e) = lw;
    }
  };

  // prologue: buf0 <- chunk0; regs <- chunk1
  prefetch(0);
  stage(0);
  prefetch(1);
  __syncthreads();

  for (int chunk = 0; chunk < 16; ++chunk) {
    const unsigned short* fh = sb + (chunk & 1) * BUFSH;
    const unsigned short* fl = fh + 5200;
    const int rem3 = (cob * 16 + chunk) * 3;

    bf16x8 AhA[4], AlA[4], AhB[4], AlB[4];   // 2-set ping-pong (static names, rule #20)
    bf16x8 Bh[4], Bl[4];

    auto loadA = [&](int tap, bf16x8* AH, bf16x8* AL) {
      #pragma unroll
      for (int mt = 0; mt < 4; ++mt) {
        int fi = (((rem3 + tap) * 8 + wm * 4 + mt) * 2) * 64 + lane;
        AH[mt] = wf8[fi];
        AL[mt] = wf8[fi + 64];
      }
    };
    auto loadB = [&](int tap) {
      #pragma unroll
      for (int nt = 0; nt < 4; ++nt) {
        int row = wn * 64 + nt * 16 + l15 + tap;
        int e = row * 40 + quad * 8;
        Bh[nt] = *(const bf16x8*)(fh + e);
        Bl[nt] = *(const bf16x8*)(fl + e);
      }
    };
    auto mfma_tap = [&](const bf16x8* AH, const bf16x8* AL) {
      __builtin_amdgcn_s_setprio(1);
      #pragma unroll
      for (int mt = 0; mt < 4; ++mt)
        #pragma unroll
        for (int nt = 0; nt < 4; ++nt) {
          acc[mt][nt] = __builtin_amdgcn_mfma_f32_16x16x32_bf16(AH[mt], Bh[nt], acc[mt][nt], 0, 0, 0);
          acc[mt][nt] = __builtin_amdgcn_mfma_f32_16x16x32_bf16(AH[mt], Bl[nt], acc[mt][nt], 0, 0, 0);
          acc[mt][nt] = __builtin_amdgcn_mfma_f32_16x16x32_bf16(AL[mt], Bh[nt], acc[mt][nt], 0, 0, 0);
        }
      __builtin_amdgcn_s_setprio(0);
    };

    loadA(0, AhA, AlA);                 // A(t0): latency hides under stage()
    if (chunk < 15) stage((chunk + 1) & 1);
    loadB(0);
    loadA(1, AhB, AlB);                 // A(t1) in flight during tap0 MFMAs
    __builtin_amdgcn_sched_barrier(0);  // keep A(t1) issue above mfma(t0)
    mfma_tap(AhA, AlA);                 // wait retires A(t0) only
    loadB(1);
    loadA(2, AhA, AlA);                 // reuse set A; in flight during tap1 MFMAs
    __builtin_amdgcn_sched_barrier(0);  // keep A(t2) issue above mfma(t1)
    mfma_tap(AhB, AlB);                 // wait retires A(t1); A(t2) may remain
    loadB(2);
    if (chunk < 14) prefetch(chunk + 2);  // youngest: stays in flight across waits
    mfma_tap(AhA, AlA);                 // wait retires A(t2), not the prefetch
    __syncthreads();
  }

  // ---- epilogue: bias + relu -> LDS half-tiles -> 21-row projection -----------
  const int sg = tid >> 5;           // 0..7 -> rows 3sg..3sg+2
  const int ll = tid & 31;
  int rc0 = 3 * sg     < 21 ? 3 * sg     : 20;
  int rc1 = 3 * sg + 1 < 21 ? 3 * sg + 1 : 20;
  int rc2 = 3 * sg + 2 < 21 ? 3 * sg + 2 : 20;
  const float* wr0 = (rc0 < 7) ? (obj_w + (size_t)rc0 * 512) : (reg_w + (size_t)(rc0 - 7) * 512);
  const float* wr1 = (rc1 < 7) ? (obj_w + (size_t)rc1 * 512) : (reg_w + (size_t)(rc1 - 7) * 512);
  const float* wr2 = (rc2 < 7) ? (obj_w + (size_t)rc2 * 512) : (reg_w + (size_t)(rc2 - 7) * 512);
  float pacc[3][4];
  #pragma unroll
  for (int q = 0; q < 3; ++q)
    #pragma unroll
    for (int m = 0; m < 4; ++m) pacc[q][m] = 0.f;

  #pragma unroll
  for (int h = 0; h < 2; ++h) {
    __syncthreads();
    if (wm == h) {
      #pragma unroll
      for (int mt = 0; mt < 4; ++mt) {
        f32x4 bv = *(const f32x4*)(cbias + cob * 128 + h * 64 + mt * 16 + quad * 4);
        #pragma unroll
        for (int nt = 0; nt < 4; ++nt) {
          int col = wn * 64 + nt * 16 + l15;
          #pragma unroll
          for (int r = 0; r < 4; ++r)
            bufp[(mt * 16 + quad * 4 + r) * 130 + col] = fmaxf(acc[mt][nt][r] + bv[r], 0.f);
        }
      }
    }
    __syncthreads();
    for (int c = 0; c < 64; ++c) {
      int cg = cob * 128 + h * 64 + c;
      float w0 = wr0[cg], w1 = wr1[cg], w2 = wr2[cg];
      #pragma unroll
      for (int m = 0; m < 4; ++m) {
        float hv = bufp[c * 130 + ll + 32 * m];
        pacc[0][m] = fmaf(w0, hv, pacc[0][m]);
        pacc[1][m] = fmaf(w1, hv, pacc[1][m]);
        pacc[2][m] = fmaf(w2, hv, pacc[2][m]);
      }
    }
  }

  const size_t ob = (size_t)b * NANCH;
  #pragma unroll
  for (int q = 0; q < 3; ++q) {
    int r = 3 * sg + q;
    if (r < 21) {
      #pragma unroll
      for (int m = 0; m < 4; ++m) {
        int l = l0 + ll + 32 * m;
        float v = pacc[q][m] + ((cob == 0) ? ((r < 7) ? obj_b[r] : reg_b[r - 7]) : 0.f);
        if (r < 7) atomicAdd(&out[OBJ_OFF + ob + (size_t)l * 7 + r], v);
        else { int rr = r - 7; atomicAdd(&out[REG_OFF + (ob + (size_t)l * 7 + (rr >> 1)) * 2 + (rr & 1)], v); }
      }
    }
  }
}

// monotone sortable bits of a float logit (total order == value order)
__device__ __forceinline__ unsigned keybits(float x) {
  unsigned u = __float_as_uint(x);
  return (u & 0x80000000u) ? ~u : (u | 0x80000000u);
}

// ---- full-chip 16-bit-key histogram (per batch), byte-swapped bin storage -----
__global__ __launch_bounds__(256) void hist_k(const float* __restrict__ out,
                                              unsigned* __restrict__ ghist) {
  const int b = blockIdx.y;
  const float* obj = out + OBJ_OFF + (size_t)b * NANCH;
  unsigned* h = ghist + (size_t)b * 65536;
  const int base = blockIdx.x * 256 + threadIdx.x;   // grid.x = 28; 28*256*8 = NANCH
  float v[8];
  #pragma unroll
  for (int k = 0; k < 8; ++k) v[k] = obj[base + k * 7168];
  #pragma unroll
  for (int k = 0; k < 8; ++k) {
    unsigned bin = keybits(v[k]) >> 16;
    unsigned phys = ((bin & 255u) << 8) | (bin >> 8);
    atomicAdd(&h[phys], 1u);
  }
}

// ---------------- per-batch top-600 -> NMS -> top-100, 1024 threads ------------
// (R10-verified; LDS 60.4 KB, all barriers full-block.)
__global__ __launch_bounds__(1024) void propose_k(float* __restrict__ out,
                                                  const unsigned* __restrict__ ghist) {
  const int b = blockIdx.x;
  const int tid = threadIdx.x;
  const int lane = tid & 63;
  const int wave = tid >> 6;

  __shared__ unsigned long long pool[PRE_K * 10];  // 48 KB; first 1024 = sort keys
  __shared__ unsigned part[1024];
  __shared__ unsigned coarse[256];
  __shared__ float bs[PRE_K], be[PRE_K], bsc[PRE_K];
  __shared__ unsigned long long vwords[10];
  __shared__ int scal[6];

  unsigned long long* keys = pool;
  const float* obj = out + OBJ_OFF + (size_t)b * NANCH;
  const unsigned* gh = ghist + (size_t)b * 65536;

  if (tid < 10) vwords[tid] = 0ull;
  if (tid == 0) scal[2] = 0;

  // ---- stage 1: per-high8 sums, 4 partials per hi8 (coalesced via byteswap) ----
  {
    const int q = tid >> 8, h8 = tid & 255;
    unsigned s = 0;
    #pragma unroll 8
    for (int lo = 0; lo < 64; ++lo) s += gh[((unsigned)(q * 64 + lo) << 8) | (unsigned)h8];
    part[tid] = s;
  }
  __syncthreads();
  if (tid < 256) coarse[tid] = part[tid] + part[tid + 256] + part[tid + 512] + part[tid + 768];
  __syncthreads();
  for (int off = 1; off < 256; off <<= 1) {       // inclusive suffix scan
    unsigned v = 0, add = 0;
    if (tid < 256) { v = coarse[tid]; add = (tid + off < 256) ? coarse[tid + off] : 0u; }
    __syncthreads();
    if (tid < 256) coarse[tid] = v + add;
    __syncthreads();
  }
  if (tid < 256) {
    unsigned sfx  = coarse[tid];
    unsigned sfx1 = (tid < 255) ? coarse[tid + 1] : 0u;
    if (sfx >= (unsigned)PRE_K && sfx1 < (unsigned)PRE_K) { scal[0] = tid; scal[1] = (int)sfx1; }
  }
  __syncthreads();
  const int hi8 = scal[0];
  const int before1 = scal[1];
  __syncthreads();
  // ---- stage 2: refine within the winning 256-bin range ----
  if (tid < 256) coarse[tid] = gh[((unsigned)tid << 8) | (unsigned)hi8];
  __syncthreads();
  for (int off = 1; off < 256; off <<= 1) {
    unsigned v = 0, add = 0;
    if (tid < 256) { v = coarse[tid]; add = (tid + off < 256) ? coarse[tid + off] : 0u; }
    __syncthreads();
    if (tid < 256) coarse[tid] = v + add;
    __syncthreads();
  }
  if (tid < 256) {
    unsigned sfx  = coarse[tid];
    unsigned sfx1 = (tid < 255) ? coarse[tid + 1] : 0u;
    if (before1 + (int)sfx >= PRE_K && before1 + (int)sfx1 < PRE_K) scal[4] = tid;
  }
  __syncthreads();
  const unsigned Tbits = ((((unsigned)hi8 << 8) | (unsigned)scal[4]) << 16);

  // ---- compaction: single pass, 7 x 8 coalesced loads in flight ----
  for (int it = 0; it < 7; ++it) {               // 7 * 8192 = NANCH
    float v[8];
    #pragma unroll
    for (int k = 0; k < 8; ++k) v[k] = obj[it * 8192 + k * 1024 + tid];
    #pragma unroll
    for (int k = 0; k < 8; ++k) {
      unsigned u = keybits(v[k]);
      if (u >= Tbits) {
        int p = atomicAdd(&scal[2], 1);
        if (p < 1024)
          keys[p] = ((unsigned long long)u << 32) |
                    (unsigned long long)(~(unsigned)(it * 8192 + k * 1024 + tid));
      }
    }
  }
  __syncthreads();
  const int cnt = scal[2];
  if (tid >= cnt) keys[tid] = 0ull;
  // ---- bitonic sort, 1 element per thread ----
  for (unsigned k = 2; k <= 1024; k <<= 1) {
    for (unsigned j = k >> 1; j > 0; j >>= 1) {
      __syncthreads();
      unsigned idx = tid, partner = idx ^ j;
      if (partner > idx) {
        unsigned long long a = keys[idx], c = keys[partner];
        bool up = ((idx & k) == 0);
        if (up ? (a < c) : (a > c)) { keys[idx] = c; keys[partner] = a; }
      }
    }
  }
  __syncthreads();
  // ---- decode top-600 ----
  if (tid < PRE_K) {
    const int t = tid;
    unsigned long long kv = keys[t];
    unsigned u  = (unsigned)(kv >> 32);
    unsigned i2 = ~((unsigned)kv);
    unsigned ub = (u & 0x80000000u) ? (u & 0x7fffffffu) : ~u;
    float logit = __uint_as_float(ub);
    float score = 1.f / (1.f + expf(-logit));
    int li = (int)(i2 / 7u);
    int a  = (int)(i2 - (unsigned)li * 7u);
    float alen = (float)(a + 1 + (a > 4 ? a - 4 : 0));
    const float* rp = out + REG_OFF + ((size_t)b * NANCH + i2) * 2;
    float tc = rp[0];
    float tw = fminf(fmaxf(rp[1], -10.f), 10.f);
    float cc = (float)li + 0.5f + tc * alen;
    float ww = alen * expf(tw);
    float s0 = cc - 0.5f * ww;
    float e0 = cc + 0.5f * ww;
    s0 = fminf(fmaxf(s0, 0.f), (float)LF);
    e0 = fminf(fmaxf(e0, 0.f), (float)LF);
    e0 = fminf(fmaxf(e0, s0 + 1e-3f), (float)LF);
    s0 = fmaxf(fminf(s0, e0 - 1e-3f), 0.f);
    bs[t] = s0; be[t] = e0; bsc[t] = score;
    if (score >= 0.1f) atomicOr(&vwords[t >> 6], 1ull << (t & 63));
  }
  __syncthreads();
  // ---- IoU suppression mask (row-major 64-bit words) ----
  for (int widx = tid; widx < PRE_K * 10; widx += 1024) {
    int j = widx / 10;
    int w = widx - j * 10;
    int base = w * 64;
    unsigned long long m = 0ull;
    if (base + 63 > j) {
      float sj = bs[j], ej = be[j];
      float wj = ej - sj;
      for (int bit = 0; bit < 64; ++bit) {
        int i3 = base + bit;
        if (i3 > j && i3 < PRE_K) {
          float inter = fmaxf(fminf(ej, be[i3]) - fmaxf(sj, bs[i3]), 0.f);
          float uni = wj + (be[i3] - bs[i3]) - inter;
          float iou = inter / fmaxf(uni, 1e-6f);
          if (iou > 0.5f) m |= (1ull << bit);
        }
      }
    }
    pool[widx] = m;
  }
  __syncthreads();
  // ---- serial NMS sweep (wave 0; early-exit at kept=100) ----
  if (wave == 0) {
    unsigned long long rem = 0ull;
    unsigned long long vw = (lane < 10) ? vwords[lane] : 0ull;
    unsigned long long mrow = (lane < 10) ? pool[lane] : 0ull;
    int kept = 0;
    for (int i3 = 0; i3 < PRE_K; ++i3) {
      unsigned long long mnext =
          (lane < 10 && (i3 + 1) < PRE_K) ? pool[(i3 + 1) * 10 + lane] : 0ull;
      unsigned long long avail = vw & ~rem;
      unsigned long long ow = __shfl(avail, i3 >> 6);
      if ((ow >> (i3 & 63)) & 1ull) {
        rem |= mrow;
        if (lane == 0) {
          out[PROPS_OFF + (size_t)b * 200 + 2 * kept]     = bs[i3];
          out[PROPS_OFF + (size_t)b * 200 + 2 * kept + 1] = be[i3];
          out[PSC_OFF + (size_t)b * 100 + kept] = bsc[i3];
          out[PM_OFF  + (size_t)b * 100 + kept] = 1.0f;
        }
        ++kept;
        if (kept >= POST_K) break;
      }
      mrow = mnext;
    }
    if (lane == 0) scal[3] = kept;
  }
  __syncthreads();
  const int kf = scal[3];
  if (tid < POST_K && tid >= kf) {
    out[PROPS_OFF + (size_t)b * 200 + 2 * tid]     = 0.f;
    out[PROPS_OFF + (size_t)b * 200 + 2 * tid + 1] = 0.f;
    out[PSC_OFF + (size_t)b * 100 + tid] = 0.f;
    out[PM_OFF  + (size_t)b * 100 + tid] = 0.f;
  }
}

extern "C" void kernel_launch(void* const* d_in, const int* in_sizes, int n_in,
                              void* d_out, int out_size, void* d_ws, size_t ws_size,
                              hipStream_t stream) {
  const float* feat = (const float*)d_in[0];
  const float* cw   = (const float*)d_in[1];
  const float* cb   = (const float*)d_in[2];
  const float* ow   = (const float*)d_in[3];
  const float* obb  = (const float*)d_in[4];
  const float* rw   = (const float*)d_in[5];
  const float* rb   = (const float*)d_in[6];
  float* out = (float*)d_out;
  unsigned short* wf = (unsigned short*)d_ws;   // 3.14 MB prefragmented split-bf16 weights
  unsigned* ghist = (unsigned*)((char*)d_ws + GHIST_OFF);

  hipLaunchKernelGGL(prep_w_k, dim3(3072), dim3(256), 0, stream, cw, wf, out, ghist);
  hipLaunchKernelGGL(conv_proj_k, dim3(64, 4, 8), dim3(256), 0, stream,
                     feat, wf, cb, ow, obb, rw, rb, out);
  hipLaunchKernelGGL(hist_k, dim3(28, 8), dim3(256), 0, stream, out, ghist);
  hipLaunchKernelGGL(propose_k, dim3(8), dim3(1024), 0, stream, out, ghist);
}

// Round 14
// 606.192 us; speedup vs baseline: 1.1036x; 1.0079x over previous
//
#include <hip/hip_runtime.h>

#define LF 8192
#define NB 8
#define NC 512
#define NA 7
#define NANCH 57344        // LF*NA
#define PRE_K 600
#define POST_K 100

// output layout (floats), concatenated in reference return order
#define OBJ_OFF   0
#define REG_OFF   458752
#define ANCH_OFF  1376256
#define PROPS_OFF 1490944
#define PSC_OFF   1492544
#define PM_OFF    1493344

// workspace layout (bytes)
#define WF_BYTES   3145728          // prefragmented split-bf16 weights
#define GHIST_OFF  WF_BYTES         // 8 batches x 65536 bins x 4B = 2 MB
#define GHIST_BYTES (8 * 65536 * 4)

typedef __attribute__((ext_vector_type(8))) short bf16x8;
typedef __attribute__((ext_vector_type(4))) float f32x4;

__device__ __forceinline__ unsigned short f2bf(float f) {   // RNE float->bf16
  unsigned u = __float_as_uint(f);
  u += 0x7fff + ((u >> 16) & 1);
  return (unsigned short)(u >> 16);
}
__device__ __forceinline__ float bf2f(unsigned short h) {
  return __uint_as_float(((unsigned)h) << 16);
}

// packed split-bf16 convert: hw = bf16(v0)|bf16(v1)<<16, lw = residual pair.
__device__ __forceinline__ void cvt_split(float v0, float v1,
                                          unsigned& hw, unsigned& lw) {
  asm("v_cvt_pk_bf16_f32 %0, %1, %2" : "=v"(hw) : "v"(v0), "v"(v1));
  float h0f = __uint_as_float(hw << 16);
  float h1f = __uint_as_float(hw & 0xffff0000u);
  asm("v_cvt_pk_bf16_f32 %0, %1, %2" : "=v"(lw) : "v"(v0 - h0f), "v"(v1 - h1f));
}

// ---- weight prep: conv_w[co][ci][tap] -> split-bf16, MFMA-A-fragment order ----
// layout: [cc=cob*16+chunk (64)][tap 3][cotl 8][split 2][lane 64][j 8]
// frag semantics: co = cob*128 + cotl*16 + (lane&15); ci = chunk*32 + (lane>>4)*8 + j
// anchors + output-zeroing + ghist-zeroing fused in (saves 1 launch + 2 memsets).
__global__ void prep_w_k(const float* __restrict__ cw, unsigned short* __restrict__ wf,
                         float* __restrict__ out, unsigned* __restrict__ ghist) {
  int o = blockIdx.x * 256 + threadIdx.x;      // 786432 items (both splits per item)
  {
    size_t z = 2 * (size_t)o;
    if (z < ANCH_OFF) {
      out[z] = 0.f;
      if (z + 1 < ANCH_OFF) out[z + 1] = 0.f;
    }
  }
  if (o < 8 * 65536) ghist[o] = 0u;            // fused ghist zero
  if (o < NANCH) {                             // fused anchors
    int l = o / 7, a = o - l * 7;
    float len = (float)(a + 1 + (a > 4 ? a - 4 : 0));   // {1,2,3,4,5,7,9}
    float c = (float)l + 0.5f;
    out[ANCH_OFF + 2 * (size_t)o]     = c - 0.5f * len;
    out[ANCH_OFF + 2 * (size_t)o + 1] = c + 0.5f * len;
  }
  if (o >= 786432) return;
  int j    = o & 7;
  int lane = (o >> 3) & 63;
  int cotl = (o >> 9) & 7;
  int rem  = o >> 12;                          // cc*3 + tap, 0..191
  int tap  = rem % 3;
  int cc   = rem / 3;                          // cob*16 + chunk
  int co = (cc >> 4) * 128 + cotl * 16 + (lane & 15);
  int ci = (cc & 15) * 32 + (lane >> 4) * 8 + j;
  float w = cw[((size_t)co * 512 + ci) * 3 + tap];
  unsigned short hi = f2bf(w);
  unsigned short lo = f2bf(w - bf2f(hi));
  size_t base = ((((size_t)rem * 8 + cotl) * 2) * 64 + lane) * 8 + j;
  wf[base] = hi;
  wf[base + 512] = lo;                         // split stride = 64*8
}

// ---- split-bf16 MFMA conv + ReLU + projection ---------------------------------
// R13-proven structure (351us @ single (64,4,8) dispatch, MfmaUtil 40, 112 VGPR).
// Experiment ledger (all falsified, do NOT retry): R3 dbuf+setprio +2%;
// R5 cvt_pk staging VALU 0%; R7 A-ping-pong +4% (kept); R4/R6 wider reg tiles
// (160/140 VGPR -> occupancy halved, -30%); R11 8-wave merge -16%;
// R12 M128xN32 reshape -12%. B-reg double-buffer blocked (+32 VGPR > 128 law).
// T3 gload_lds path incompatible with split-bf16 conversion staging; m232:
// 8-phase at 128-sq tile = null. This is the structure-family optimum.
// HARD LAW: VGPR <=128. CAP LAW: no 2nd __launch_bounds__ arg.
#define BUFSH 10400   // shorts per buffer (fhi 5200 + flo 5200)
__global__ __launch_bounds__(256) void conv_proj_k(
    const float* __restrict__ feat, const unsigned short* __restrict__ wfrag,
    const float* __restrict__ cbias, const float* __restrict__ obj_w,
    const float* __restrict__ obj_b, const float* __restrict__ reg_w,
    const float* __restrict__ reg_b, float* __restrict__ out)
{
  __shared__ __align__(16) char smem[41600];   // 2 feat buffers; epilogue bufp aliases
  unsigned short* sb = (unsigned short*)smem;
  float* bufp = (float*)smem;                  // [64][130] (33280 B, aliases bufs)

  const int tid  = threadIdx.x;
  const int l0   = blockIdx.x * 128;
  const int cob  = blockIdx.y;
  const int b    = blockIdx.z;
  const int lane = tid & 63, wave = tid >> 6;
  const int wm = wave >> 1, wn = wave & 1;
  const int quad = lane >> 4, l15 = lane & 15;

  const float* fb = feat + (size_t)b * 512 * LF;
  const bf16x8* wf8 = (const bf16x8*)wfrag;

  f32x4 acc[4][4];
  #pragma unroll
  for (int mt = 0; mt < 4; ++mt)
    #pragma unroll
    for (int nt = 0; nt < 4; ++nt) acc[mt][nt] = (f32x4){0.f, 0.f, 0.f, 0.f};

  const int r8 = tid & 7, cp2 = (tid >> 3) & 15, set = tid >> 7;

  // boundary-thread geometry (tid < 32 handles rows 0 and 129)
  const int brr = tid >> 4, bc2 = tid & 15;
  const int bl = (brr == 0) ? (l0 - 1) : (l0 + 128);
  const bool bok = (bl >= 0) && (bl < LF);

  float pv0[8], pv1[8], bv0 = 0.f, bv1 = 0.f;

  auto prefetch = [&](int ch) {
    const int cb = ch * 32;
    #pragma unroll
    for (int p = 0; p < 8; ++p) {
      int l = l0 + p * 16 + set * 8 + r8;
      pv0[p] = fb[(size_t)(cb + 2 * cp2) * LF + l];
      pv1[p] = fb[(size_t)(cb + 2 * cp2 + 1) * LF + l];
    }
    if (tid < 32 && bok) {
      bv0 = fb[(size_t)(cb + 2 * bc2) * LF + bl];
      bv1 = fb[(size_t)(cb + 2 * bc2 + 1) * LF + bl];
    }
  };
  auto stage = [&](int bi) {       // convert pv/bv -> LDS buffer bi (packed cvt)
    unsigned short* fh = sb + bi * BUFSH;
    unsigned short* fl = fh + 5200;
    #pragma unroll
    for (int p = 0; p < 8; ++p) {
      int row = p * 16 + set * 8 + r8;
      unsigned hw, lw;
      cvt_split(pv0[p], pv1[p], hw, lw);
      int e = (row + 1) * 40 + 2 * cp2;
      *(unsigned*)(fh + e) = hw;
      *(unsigned*)(fl + e) = lw;
    }
    if (tid < 32) {
      unsigned hw, lw;
      cvt_split(bv0, bv1, hw, lw);
      int e = (brr * 129) * 40 + 2 * bc2;
      *(unsigned*)(fh + e) = hw;
      *(unsigned*)(fl + e) = lw;
    }
  };

  // prologue: buf0 <- chunk0; regs <- chunk1
  prefetch(0);
  stage(0);
  prefetch(1);
  __syncthreads();

  for (int chunk = 0; chunk < 16; ++chunk) {
    const unsigned short* fh = sb + (chunk & 1) * BUFSH;
    const unsigned short* fl = fh + 5200;
    const int rem3 = (cob * 16 + chunk) * 3;

    bf16x8 AhA[4], AlA[4], AhB[4], AlB[4];   // 2-set ping-pong (static names, rule #20)
    bf16x8 Bh[4], Bl[4];

    auto loadA = [&](int tap, bf16x8* AH, bf16x8* AL) {
      #pragma unroll
      for (int mt = 0; mt < 4; ++mt) {
        int fi = (((rem3 + tap) * 8 + wm * 4 + mt) * 2) * 64 + lane;
        AH[mt] = wf8[fi];
        AL[mt] = wf8[fi + 64];
      }
    };
    auto loadB = [&](int tap) {
      #pragma unroll
      for (int nt = 0; nt < 4; ++nt) {
        int row = wn * 64 + nt * 16 + l15 + tap;
        int e = row * 40 + quad * 8;
        Bh[nt] = *(const bf16x8*)(fh + e);
        Bl[nt] = *(const bf16x8*)(fl + e);
      }
    };
    auto mfma_tap = [&](const bf16x8* AH, const bf16x8* AL) {
      __builtin_amdgcn_s_setprio(1);
      #pragma unroll
      for (int mt = 0; mt < 4; ++mt)
        #pragma unroll
        for (int nt = 0; nt < 4; ++nt) {
          acc[mt][nt] = __builtin_amdgcn_mfma_f32_16x16x32_bf16(AH[mt], Bh[nt], acc[mt][nt], 0, 0, 0);
          acc[mt][nt] = __builtin_amdgcn_mfma_f32_16x16x32_bf16(AH[mt], Bl[nt], acc[mt][nt], 0, 0, 0);
          acc[mt][nt] = __builtin_amdgcn_mfma_f32_16x16x32_bf16(AL[mt], Bh[nt], acc[mt][nt], 0, 0, 0);
        }
      __builtin_amdgcn_s_setprio(0);
    };

    loadA(0, AhA, AlA);                 // A(t0): latency hides under stage()
    if (chunk < 15) stage((chunk + 1) & 1);
    loadB(0);
    loadA(1, AhB, AlB);                 // A(t1) in flight during tap0 MFMAs
    __builtin_amdgcn_sched_barrier(0);  // keep A(t1) issue above mfma(t0)
    mfma_tap(AhA, AlA);                 // wait retires A(t0) only
    loadB(1);
    loadA(2, AhA, AlA);                 // reuse set A; in flight during tap1 MFMAs
    __builtin_amdgcn_sched_barrier(0);  // keep A(t2) issue above mfma(t1)
    mfma_tap(AhB, AlB);                 // wait retires A(t1); A(t2) may remain
    loadB(2);
    if (chunk < 14) prefetch(chunk + 2);  // youngest: stays in flight across waits
    mfma_tap(AhA, AlA);                 // wait retires A(t2), not the prefetch
    __syncthreads();
  }

  // ---- epilogue: bias + relu -> LDS half-tiles -> 21-row projection -----------
  const int sg = tid >> 5;           // 0..7 -> rows 3sg..3sg+2
  const int ll = tid & 31;
  int rc0 = 3 * sg     < 21 ? 3 * sg     : 20;
  int rc1 = 3 * sg + 1 < 21 ? 3 * sg + 1 : 20;
  int rc2 = 3 * sg + 2 < 21 ? 3 * sg + 2 : 20;
  const float* wr0 = (rc0 < 7) ? (obj_w + (size_t)rc0 * 512) : (reg_w + (size_t)(rc0 - 7) * 512);
  const float* wr1 = (rc1 < 7) ? (obj_w + (size_t)rc1 * 512) : (reg_w + (size_t)(rc1 - 7) * 512);
  const float* wr2 = (rc2 < 7) ? (obj_w + (size_t)rc2 * 512) : (reg_w + (size_t)(rc2 - 7) * 512);
  float pacc[3][4];
  #pragma unroll
  for (int q = 0; q < 3; ++q)
    #pragma unroll
    for (int m = 0; m < 4; ++m) pacc[q][m] = 0.f;

  #pragma unroll
  for (int h = 0; h < 2; ++h) {
    __syncthreads();
    if (wm == h) {
      #pragma unroll
      for (int mt = 0; mt < 4; ++mt) {
        f32x4 bv = *(const f32x4*)(cbias + cob * 128 + h * 64 + mt * 16 + quad * 4);
        #pragma unroll
        for (int nt = 0; nt < 4; ++nt) {
          int col = wn * 64 + nt * 16 + l15;
          #pragma unroll
          for (int r = 0; r < 4; ++r)
            bufp[(mt * 16 + quad * 4 + r) * 130 + col] = fmaxf(acc[mt][nt][r] + bv[r], 0.f);
        }
      }
    }
    __syncthreads();
    for (int c = 0; c < 64; ++c) {
      int cg = cob * 128 + h * 64 + c;
      float w0 = wr0[cg], w1 = wr1[cg], w2 = wr2[cg];
      #pragma unroll
      for (int m = 0; m < 4; ++m) {
        float hv = bufp[c * 130 + ll + 32 * m];
        pacc[0][m] = fmaf(w0, hv, pacc[0][m]);
        pacc[1][m] = fmaf(w1, hv, pacc[1][m]);
        pacc[2][m] = fmaf(w2, hv, pacc[2][m]);
      }
    }
  }

  const size_t ob = (size_t)b * NANCH;
  #pragma unroll
  for (int q = 0; q < 3; ++q) {
    int r = 3 * sg + q;
    if (r < 21) {
      #pragma unroll
      for (int m = 0; m < 4; ++m) {
        int l = l0 + ll + 32 * m;
        float v = pacc[q][m] + ((cob == 0) ? ((r < 7) ? obj_b[r] : reg_b[r - 7]) : 0.f);
        if (r < 7) atomicAdd(&out[OBJ_OFF + ob + (size_t)l * 7 + r], v);
        else { int rr = r - 7; atomicAdd(&out[REG_OFF + (ob + (size_t)l * 7 + (rr >> 1)) * 2 + (rr & 1)], v); }
      }
    }
  }
}

// monotone sortable bits of a float logit (total order == value order)
__device__ __forceinline__ unsigned keybits(float x) {
  unsigned u = __float_as_uint(x);
  return (u & 0x80000000u) ? ~u : (u | 0x80000000u);
}

// ---- full-chip 16-bit-key histogram (per batch), byte-swapped bin storage -----
__global__ __launch_bounds__(256) void hist_k(const float* __restrict__ out,
                                              unsigned* __restrict__ ghist) {
  const int b = blockIdx.y;
  const float* obj = out + OBJ_OFF + (size_t)b * NANCH;
  unsigned* h = ghist + (size_t)b * 65536;
  const int base = blockIdx.x * 256 + threadIdx.x;   // grid.x = 28; 28*256*8 = NANCH
  float v[8];
  #pragma unroll
  for (int k = 0; k < 8; ++k) v[k] = obj[base + k * 7168];
  #pragma unroll
  for (int k = 0; k < 8; ++k) {
    unsigned bin = keybits(v[k]) >> 16;
    unsigned phys = ((bin & 255u) << 8) | (bin >> 8);
    atomicAdd(&h[phys], 1u);
  }
}

// ---------------- per-batch top-600 -> NMS -> top-100, 1024 threads ------------
// R14: NMS sweep mask-row prefetch batched 8-deep (was 1-deep). The sweep's 600
// iterations each waited ~120cyc on a dependent LDS row load (~30us serial, on
// 1 wave while 15 idle). 8 statically-named rows in flight (rule #20: no
// runtime-indexed reg arrays) cut exposed latency ~8x. Output semantics
// identical (mask rows static; kept<POST_K guard == early break).
// LDS 60.4 KB, all barriers full-block.
__global__ __launch_bounds__(1024) void propose_k(float* __restrict__ out,
                                                  const unsigned* __restrict__ ghist) {
  const int b = blockIdx.x;
  const int tid = threadIdx.x;
  const int lane = tid & 63;
  const int wave = tid >> 6;

  __shared__ unsigned long long pool[PRE_K * 10];  // 48 KB; first 1024 = sort keys
  __shared__ unsigned part[1024];
  __shared__ unsigned coarse[256];
  __shared__ float bs[PRE_K], be[PRE_K], bsc[PRE_K];
  __shared__ unsigned long long vwords[10];
  __shared__ int scal[6];

  unsigned long long* keys = pool;
  const float* obj = out + OBJ_OFF + (size_t)b * NANCH;
  const unsigned* gh = ghist + (size_t)b * 65536;

  if (tid < 10) vwords[tid] = 0ull;
  if (tid == 0) scal[2] = 0;

  // ---- stage 1: per-high8 sums, 4 partials per hi8 (coalesced via byteswap) ----
  {
    const int q = tid >> 8, h8 = tid & 255;
    unsigned s = 0;
    #pragma unroll 8
    for (int lo = 0; lo < 64; ++lo) s += gh[((unsigned)(q * 64 + lo) << 8) | (unsigned)h8];
    part[tid] = s;
  }
  __syncthreads();
  if (tid < 256) coarse[tid] = part[tid] + part[tid + 256] + part[tid + 512] + part[tid + 768];
  __syncthreads();
  for (int off = 1; off < 256; off <<= 1) {       // inclusive suffix scan
    unsigned v = 0, add = 0;
    if (tid < 256) { v = coarse[tid]; add = (tid + off < 256) ? coarse[tid + off] : 0u; }
    __syncthreads();
    if (tid < 256) coarse[tid] = v + add;
    __syncthreads();
  }
  if (tid < 256) {
    unsigned sfx  = coarse[tid];
    unsigned sfx1 = (tid < 255) ? coarse[tid + 1] : 0u;
    if (sfx >= (unsigned)PRE_K && sfx1 < (unsigned)PRE_K) { scal[0] = tid; scal[1] = (int)sfx1; }
  }
  __syncthreads();
  const int hi8 = scal[0];
  const int before1 = scal[1];
  __syncthreads();
  // ---- stage 2: refine within the winning 256-bin range ----
  if (tid < 256) coarse[tid] = gh[((unsigned)tid << 8) | (unsigned)hi8];
  __syncthreads();
  for (int off = 1; off < 256; off <<= 1) {
    unsigned v = 0, add = 0;
    if (tid < 256) { v = coarse[tid]; add = (tid + off < 256) ? coarse[tid + off] : 0u; }
    __syncthreads();
    if (tid < 256) coarse[tid] = v + add;
    __syncthreads();
  }
  if (tid < 256) {
    unsigned sfx  = coarse[tid];
    unsigned sfx1 = (tid < 255) ? coarse[tid + 1] : 0u;
    if (before1 + (int)sfx >= PRE_K && before1 + (int)sfx1 < PRE_K) scal[4] = tid;
  }
  __syncthreads();
  const unsigned Tbits = ((((unsigned)hi8 << 8) | (unsigned)scal[4]) << 16);

  // ---- compaction: single pass, 7 x 8 coalesced loads in flight ----
  for (int it = 0; it < 7; ++it) {               // 7 * 8192 = NANCH
    float v[8];
    #pragma unroll
    for (int k = 0; k < 8; ++k) v[k] = obj[it * 8192 + k * 1024 + tid];
    #pragma unroll
    for (int k = 0; k < 8; ++k) {
      unsigned u = keybits(v[k]);
      if (u >= Tbits) {
        int p = atomicAdd(&scal[2], 1);
        if (p < 1024)
          keys[p] = ((unsigned long long)u << 32) |
                    (unsigned long long)(~(unsigned)(it * 8192 + k * 1024 + tid));
      }
    }
  }
  __syncthreads();
  const int cnt = scal[2];
  if (tid >= cnt) keys[tid] = 0ull;
  // ---- bitonic sort, 1 element per thread ----
  for (unsigned k = 2; k <= 1024; k <<= 1) {
    for (unsigned j = k >> 1; j > 0; j >>= 1) {
      __syncthreads();
      unsigned idx = tid, partner = idx ^ j;
      if (partner > idx) {
        unsigned long long a = keys[idx], c = keys[partner];
        bool up = ((idx & k) == 0);
        if (up ? (a < c) : (a > c)) { keys[idx] = c; keys[partner] = a; }
      }
    }
  }
  __syncthreads();
  // ---- decode top-600 ----
  if (tid < PRE_K) {
    const int t = tid;
    unsigned long long kv = keys[t];
    unsigned u  = (unsigned)(kv >> 32);
    unsigned i2 = ~((unsigned)kv);
    unsigned ub = (u & 0x80000000u) ? (u & 0x7fffffffu) : ~u;
    float logit = __uint_as_float(ub);
    float score = 1.f / (1.f + expf(-logit));
    int li = (int)(i2 / 7u);
    int a  = (int)(i2 - (unsigned)li * 7u);
    float alen = (float)(a + 1 + (a > 4 ? a - 4 : 0));
    const float* rp = out + REG_OFF + ((size_t)b * NANCH + i2) * 2;
    float tc = rp[0];
    float tw = fminf(fmaxf(rp[1], -10.f), 10.f);
    float cc = (float)li + 0.5f + tc * alen;
    float ww = alen * expf(tw);
    float s0 = cc - 0.5f * ww;
    float e0 = cc + 0.5f * ww;
    s0 = fminf(fmaxf(s0, 0.f), (float)LF);
    e0 = fminf(fmaxf(e0, 0.f), (float)LF);
    e0 = fminf(fmaxf(e0, s0 + 1e-3f), (float)LF);
    s0 = fmaxf(fminf(s0, e0 - 1e-3f), 0.f);
    bs[t] = s0; be[t] = e0; bsc[t] = score;
    if (score >= 0.1f) atomicOr(&vwords[t >> 6], 1ull << (t & 63));
  }
  __syncthreads();
  // ---- IoU suppression mask (row-major 64-bit words) ----
  for (int widx = tid; widx < PRE_K * 10; widx += 1024) {
    int j = widx / 10;
    int w = widx - j * 10;
    int base = w * 64;
    unsigned long long m = 0ull;
    if (base + 63 > j) {
      float sj = bs[j], ej = be[j];
      float wj = ej - sj;
      for (int bit = 0; bit < 64; ++bit) {
        int i3 = base + bit;
        if (i3 > j && i3 < PRE_K) {
          float inter = fmaxf(fminf(ej, be[i3]) - fmaxf(sj, bs[i3]), 0.f);
          float uni = wj + (be[i3] - bs[i3]) - inter;
          float iou = inter / fmaxf(uni, 1e-6f);
          if (iou > 0.5f) m |= (1ull << bit);
        }
      }
    }
    pool[widx] = m;
  }
  __syncthreads();
  // ---- serial NMS sweep (wave 0), 8-deep mask-row prefetch ----
  if (wave == 0) {
    unsigned long long rem = 0ull;
    unsigned long long vw = (lane < 10) ? vwords[lane] : 0ull;
    unsigned long long mrow = (lane < 10) ? pool[lane] : 0ull;
    int kept = 0;
    for (int g = 0; g < PRE_K && kept < POST_K; g += 8) {
      // prefetch rows g+1..g+8 into static regs (8 LDS loads in flight)
      unsigned long long n0 = (lane < 10 && g + 1 < PRE_K) ? pool[(g + 1) * 10 + lane] : 0ull;
      unsigned long long n1 = (lane < 10 && g + 2 < PRE_K) ? pool[(g + 2) * 10 + lane] : 0ull;
      unsigned long long n2 = (lane < 10 && g + 3 < PRE_K) ? pool[(g + 3) * 10 + lane] : 0ull;
      unsigned long long n3 = (lane < 10 && g + 4 < PRE_K) ? pool[(g + 4) * 10 + lane] : 0ull;
      unsigned long long n4 = (lane < 10 && g + 5 < PRE_K) ? pool[(g + 5) * 10 + lane] : 0ull;
      unsigned long long n5 = (lane < 10 && g + 6 < PRE_K) ? pool[(g + 6) * 10 + lane] : 0ull;
      unsigned long long n6 = (lane < 10 && g + 7 < PRE_K) ? pool[(g + 7) * 10 + lane] : 0ull;
      unsigned long long n7 = (lane < 10 && g + 8 < PRE_K) ? pool[(g + 8) * 10 + lane] : 0ull;
      #pragma unroll
      for (int k = 0; k < 8; ++k) {
        int i3 = g + k;
        if (i3 < PRE_K) {
          unsigned long long avail = vw & ~rem;
          unsigned long long ow = __shfl(avail, i3 >> 6);
          if (((ow >> (i3 & 63)) & 1ull) && kept < POST_K) {
            rem |= mrow;
            if (lane == 0) {
              out[PROPS_OFF + (size_t)b * 200 + 2 * kept]     = bs[i3];
              out[PROPS_OFF + (size_t)b * 200 + 2 * kept + 1] = be[i3];
              out[PSC_OFF + (size_t)b * 100 + kept] = bsc[i3];
              out[PM_OFF  + (size_t)b * 100 + kept] = 1.0f;
            }
            ++kept;
          }
        }
        // advance to next prefetched row (static select folds per unrolled k)
        mrow = (k == 0) ? n0 : (k == 1) ? n1 : (k == 2) ? n2 : (k == 3) ? n3
             : (k == 4) ? n4 : (k == 5) ? n5 : (k == 6) ? n6 : n7;
      }
    }
    if (lane == 0) scal[3] = kept;
  }
  __syncthreads();
  const int kf = scal[3];
  if (tid < POST_K && tid >= kf) {
    out[PROPS_OFF + (size_t)b * 200 + 2 * tid]     = 0.f;
    out[PROPS_OFF + (size_t)b * 200 + 2 * tid + 1] = 0.f;
    out[PSC_OFF + (size_t)b * 100 + tid] = 0.f;
    out[PM_OFF  + (size_t)b * 100 + tid] = 0.f;
  }
}

extern "C" void kernel_launch(void* const* d_in, const int* in_sizes, int n_in,
                              void* d_out, int out_size, void* d_ws, size_t ws_size,
                              hipStream_t stream) {
  const float* feat = (const float*)d_in[0];
  const float* cw   = (const float*)d_in[1];
  const float* cb   = (const float*)d_in[2];
  const float* ow   = (const float*)d_in[3];
  const float* obb  = (const float*)d_in[4];
  const float* rw   = (const float*)d_in[5];
  const float* rb   = (const float*)d_in[6];
  float* out = (float*)d_out;
  unsigned short* wf = (unsigned short*)d_ws;   // 3.14 MB prefragmented split-bf16 weights
  unsigned* ghist = (unsigned*)((char*)d_ws + GHIST_OFF);

  hipLaunchKernelGGL(prep_w_k, dim3(3072), dim3(256), 0, stream, cw, wf, out, ghist);
  hipLaunchKernelGGL(conv_proj_k, dim3(64, 4, 8), dim3(256), 0, stream,
                     feat, wf, cb, ow, obb, rw, rb, out);
  hipLaunchKernelGGL(hist_k, dim3(28, 8), dim3(256), 0, stream, out, ghist);
  hipLaunchKernelGGL(propose_k, dim3(8), dim3(1024), 0, stream, out, ghist);
}